// Round 1
// baseline (1055.817 us; speedup 1.0000x reference)
//
#include <hip/hip_runtime.h>
#include <hip/hip_bf16.h>

#define N_NODES 50000
#define N_EDGES 800000
#define C_IN    128
#define C_H     64
#define N_LAYER 9
#define N_GRAPH 10
#define N_PER_G 5000

// ---------------- CSR build ----------------

__global__ void count_kernel(const int* __restrict__ dst, int* __restrict__ cnt, int e) {
    int i = blockIdx.x * blockDim.x + threadIdx.x;
    if (i < e) atomicAdd(&cnt[dst[i]], 1);
}

// single-block exclusive scan over cnt -> rowStart, cursor; also dinv = rsqrt(cnt+1)
__global__ __launch_bounds__(1024) void scan_kernel(const int* __restrict__ cnt,
                                                    int* __restrict__ rowStart,
                                                    int* __restrict__ cursor,
                                                    float* __restrict__ dinv,
                                                    int n) {
    __shared__ int sdata[1024];
    int running = 0;
    for (int base = 0; base < n; base += 1024) {
        int idx = base + threadIdx.x;
        int v = (idx < n) ? cnt[idx] : 0;
        sdata[threadIdx.x] = v;
        __syncthreads();
        for (int off = 1; off < 1024; off <<= 1) {
            int t = sdata[threadIdx.x];
            int add = (threadIdx.x >= off) ? sdata[threadIdx.x - off] : 0;
            __syncthreads();
            sdata[threadIdx.x] = t + add;
            __syncthreads();
        }
        int incl = sdata[threadIdx.x];
        int excl = incl - v;
        if (idx < n) {
            int rs = running + excl;
            rowStart[idx] = rs;
            cursor[idx] = rs;
            dinv[idx] = rsqrtf((float)v + 1.0f);
        }
        running += sdata[1023];
        __syncthreads();
    }
}

__global__ void scatter_kernel(const int* __restrict__ src, const int* __restrict__ dst,
                               int* __restrict__ cursor, const float* __restrict__ dinv,
                               int* __restrict__ csr_src, float* __restrict__ csr_w, int e) {
    int i = blockIdx.x * blockDim.x + threadIdx.x;
    if (i < e) {
        int d = dst[i], s = src[i];
        int p = atomicAdd(&cursor[d], 1);
        csr_src[p] = s;
        csr_w[p] = dinv[s] * dinv[d];
    }
}

// ---------------- layer 0 input GEMM: hw0 = x @ W0  (K=128) ----------------

__global__ __launch_bounds__(256) void gemm0_kernel(const float* __restrict__ x,
                                                    const float* __restrict__ W0,
                                                    float* __restrict__ out, int n) {
    __shared__ float Wlds[C_IN * C_H];   // 32 KB
    __shared__ float xl[4 * C_IN];       // 2 KB
    for (int t = threadIdx.x; t < C_IN * C_H; t += 256) Wlds[t] = W0[t];
    for (int t = threadIdx.x; t < 4 * C_IN; t += 256) {
        int r = blockIdx.x * 4 + t / C_IN;
        xl[t] = (r < n) ? x[r * C_IN + (t & (C_IN - 1))] : 0.f;
    }
    __syncthreads();
    int wave = threadIdx.x >> 6, lane = threadIdx.x & 63;
    int i = blockIdx.x * 4 + wave;
    if (i >= n) return;
    float o = 0.f;
#pragma unroll 8
    for (int k = 0; k < C_IN; k++) o += xl[wave * C_IN + k] * Wlds[k * C_H + lane];
    out[i * C_H + lane] = o;
}

// ---------------- fused layer: aggregate(hw) -> relu(+b) -> @Wnext ----------------

__global__ __launch_bounds__(256) void layer_kernel(const float* __restrict__ hw,
                                                    const int* __restrict__ rowStart,
                                                    const int* __restrict__ cnt,
                                                    const int* __restrict__ csr_src,
                                                    const float* __restrict__ csr_w,
                                                    const float* __restrict__ dinv,
                                                    const float* __restrict__ bias,
                                                    const float* __restrict__ Wnext,
                                                    float* __restrict__ out, int n) {
    __shared__ float Wlds[C_H * C_H];  // 16 KB
    for (int t = threadIdx.x; t < C_H * C_H; t += 256) Wlds[t] = Wnext[t];
    __syncthreads();
    int wave = threadIdx.x >> 6, lane = threadIdx.x & 63;
    int i = blockIdx.x * 4 + wave;
    if (i >= n) return;

    float di = dinv[i];
    float acc = hw[i * C_H + lane] * (di * di);   // self-loop term
    int start = rowStart[i];
    int deg = cnt[i];
    for (int base = 0; base < deg; base += 64) {
        int m = deg - base; if (m > 64) m = 64;
        int s = 0; float w = 0.f;
        if (lane < m) {
            s = csr_src[start + base + lane];
            w = csr_w[start + base + lane];
        }
        for (int j = 0; j < m; j++) {
            int   sj = __shfl(s, j);
            float wj = __shfl(w, j);
            acc += hw[sj * C_H + lane] * wj;
        }
    }
    float h = acc + bias[lane];
    h = h > 0.f ? h : 0.f;

    // GEMV: out[i][lane] = sum_k h_k * Wnext[k][lane]
    float o = 0.f;
#pragma unroll 8
    for (int k = 0; k < C_H; k++) {
        float hk = __shfl(h, k);
        o += hk * Wlds[k * C_H + lane];
    }
    out[i * C_H + lane] = o;
}

// ---------------- pooling head ----------------

__global__ __launch_bounds__(256) void pool_kernel(const float* __restrict__ hn,
                                                   float* __restrict__ poolbuf) {
    int g = blockIdx.x >> 4;      // graph
    int s = blockIdx.x & 15;      // slice
    int lane = threadIdx.x & 63;
    int rg = threadIdx.x >> 6;    // 0..3
    int stream = s * 4 + rg;      // 0..63
    float acc = 0.f;
    for (int r = stream; r < N_PER_G; r += 64)
        acc += hn[(g * N_PER_G + r) * C_H + lane];
    __shared__ float red[4][C_H];
    red[rg][lane] = acc;
    __syncthreads();
    if (rg == 0) {
        float t = red[0][lane] + red[1][lane] + red[2][lane] + red[3][lane];
        atomicAdd(&poolbuf[g * C_H + lane], t);
    }
}

__global__ void poolwp_kernel(const float* __restrict__ poolbuf,
                              const float* __restrict__ Wp,
                              float* __restrict__ poolwp) {
    int g = blockIdx.x, c = threadIdx.x;
    float o = 0.f;
#pragma unroll 8
    for (int k = 0; k < C_H; k++) o += poolbuf[g * C_H + k] * Wp[k * C_H + c];
    poolwp[g * C_H + c] = o;
}

__global__ __launch_bounds__(256) void final_kernel(const float* __restrict__ hn,
                                                    const float* __restrict__ poolwp,
                                                    const float* __restrict__ Wa,
                                                    float* __restrict__ out, int n) {
    int wave = threadIdx.x >> 6, lane = threadIdx.x & 63;
    int i = blockIdx.x * 4 + wave;
    if (i >= n) return;
    int g = i / N_PER_G;
    float v = fmaxf(hn[i * C_H + lane], 0.f) * Wa[lane]
            + fmaxf(poolwp[g * C_H + lane], 0.f) * Wa[C_H + lane];
#pragma unroll
    for (int off = 32; off; off >>= 1) v += __shfl_down(v, off);
    if (lane == 0) out[i] = tanhf(v);
}

// ---------------- launch ----------------

extern "C" void kernel_launch(void* const* d_in, const int* in_sizes, int n_in,
                              void* d_out, int out_size, void* d_ws, size_t ws_size,
                              hipStream_t stream) {
    const float* x   = (const float*)d_in[0];
    const int*   ei  = (const int*)d_in[1];
    const float* W0  = (const float*)d_in[2];
    const float* b0  = (const float*)d_in[3];
    const float* Ws  = (const float*)d_in[4];
    const float* bs  = (const float*)d_in[5];
    const float* Wn  = (const float*)d_in[6];
    const float* Wp  = (const float*)d_in[7];
    const float* Wa  = (const float*)d_in[8];
    float* out = (float*)d_out;

    const int* e_src = ei;
    const int* e_dst = ei + N_EDGES;

    // workspace carve-up
    size_t off = 0;
    auto alloc = [&](size_t bytes) { size_t o = off; off = (off + bytes + 255) & ~(size_t)255; return o; };
    char* ws = (char*)d_ws;
    int*   cnt      = (int*)  (ws + alloc(N_NODES * 4));
    int*   rowStart = (int*)  (ws + alloc(N_NODES * 4));
    int*   cursor   = (int*)  (ws + alloc(N_NODES * 4));
    float* dinv     = (float*)(ws + alloc(N_NODES * 4));
    int*   csr_src  = (int*)  (ws + alloc(N_EDGES * 4));
    float* csr_w    = (float*)(ws + alloc(N_EDGES * 4));
    float* bufA     = (float*)(ws + alloc((size_t)N_NODES * C_H * 4));
    float* bufB     = (float*)(ws + alloc((size_t)N_NODES * C_H * 4));
    float* poolbuf  = (float*)(ws + alloc(N_GRAPH * C_H * 4));
    float* poolwp   = (float*)(ws + alloc(N_GRAPH * C_H * 4));

    hipMemsetAsync(cnt, 0, N_NODES * 4, stream);
    hipMemsetAsync(poolbuf, 0, N_GRAPH * C_H * 4, stream);

    const int EB = (N_EDGES + 255) / 256;
    count_kernel<<<EB, 256, 0, stream>>>(e_dst, cnt, N_EDGES);
    scan_kernel<<<1, 1024, 0, stream>>>(cnt, rowStart, cursor, dinv, N_NODES);
    scatter_kernel<<<EB, 256, 0, stream>>>(e_src, e_dst, cursor, dinv, csr_src, csr_w, N_EDGES);

    const int NB = (N_NODES + 3) / 4;
    gemm0_kernel<<<NB, 256, 0, stream>>>(x, W0, bufA, N_NODES);  // hw0 = x @ W0

    // 9 fused layers; layer k consumes hw_k, applies bias b_k, multiplies by W_{k+1} (Wn for k=8)
    for (int k = 0; k < N_LAYER; k++) {
        const float* hin  = (k & 1) ? bufB : bufA;
        float*       hout = (k & 1) ? bufA : bufB;
        const float* bias  = (k == 0) ? b0 : (bs + (k - 1) * C_H);
        const float* Wnext = (k < N_LAYER - 1) ? (Ws + k * C_H * C_H) : Wn;
        layer_kernel<<<NB, 256, 0, stream>>>(hin, rowStart, cnt, csr_src, csr_w,
                                             dinv, bias, Wnext, hout, N_NODES);
    }
    // hn (post node_transform) ends up in bufB (layer 8 reads bufA, writes bufB)
    const float* hn = bufB;

    pool_kernel<<<N_GRAPH * 16, 256, 0, stream>>>(hn, poolbuf);
    poolwp_kernel<<<N_GRAPH, C_H, 0, stream>>>(poolbuf, Wp, poolwp);
    final_kernel<<<NB, 256, 0, stream>>>(hn, poolwp, Wa, out, N_NODES);
}

// Round 2
// 782.200 us; speedup vs baseline: 1.3498x; 1.3498x over previous
//
#include <hip/hip_runtime.h>
#include <hip/hip_bf16.h>

#define N_NODES 50000
#define N_EDGES 800000
#define C_IN    128
#define C_H     64
#define N_LAYER 9
#define N_GRAPH 10
#define N_PER_G 5000

// ---------------- CSR build ----------------

__global__ void count_kernel(const int* __restrict__ dst, int* __restrict__ cnt, int e) {
    int i = blockIdx.x * blockDim.x + threadIdx.x;
    if (i < e) atomicAdd(&cnt[dst[i]], 1);
}

// one block, 1024 threads: thread-serial partial sums + single block scan
__global__ __launch_bounds__(1024) void scan_kernel(const int* __restrict__ cnt,
                                                    int* __restrict__ rowStart,
                                                    int* __restrict__ cursor,
                                                    float* __restrict__ dinv,
                                                    int n) {
    const int PER = 49;  // ceil(50000/1024)
    int t = threadIdx.x;
    int base = t * PER;
    int s = 0;
    for (int j = 0; j < PER; j++) {
        int idx = base + j;
        if (idx < n) s += cnt[idx];
    }
    __shared__ int sd[1024];
    sd[t] = s;
    __syncthreads();
    for (int off = 1; off < 1024; off <<= 1) {
        int v = sd[t];
        int add = (t >= off) ? sd[t - off] : 0;
        __syncthreads();
        sd[t] = v + add;
        __syncthreads();
    }
    int run = sd[t] - s;  // exclusive prefix
    for (int j = 0; j < PER; j++) {
        int idx = base + j;
        if (idx < n) {
            int c = cnt[idx];
            rowStart[idx] = run;
            cursor[idx] = run;
            dinv[idx] = rsqrtf((float)c + 1.0f);
            run += c;
        }
    }
}

// pack (src, weight) into int2 per edge
__global__ void scatter_kernel(const int* __restrict__ src, const int* __restrict__ dst,
                               int* __restrict__ cursor, const float* __restrict__ dinv,
                               int2* __restrict__ csr_sw, int e) {
    int i = blockIdx.x * blockDim.x + threadIdx.x;
    if (i < e) {
        int d = dst[i], s = src[i];
        int p = atomicAdd(&cursor[d], 1);
        float w = dinv[s] * dinv[d];
        csr_sw[p] = make_int2(s, __float_as_int(w));
    }
}

// ---------------- layer 0 input GEMM: hw0 = x @ W0  (K=128) ----------------

__global__ __launch_bounds__(256) void gemm0_kernel(const float* __restrict__ x,
                                                    const float* __restrict__ W0,
                                                    float* __restrict__ out, int n) {
    __shared__ float Wlds[C_IN * C_H];   // 32 KB
    __shared__ float xl[4 * C_IN];       // 2 KB
    for (int t = threadIdx.x; t < C_IN * C_H; t += 256) Wlds[t] = W0[t];
    for (int t = threadIdx.x; t < 4 * C_IN; t += 256) {
        int r = blockIdx.x * 4 + t / C_IN;
        xl[t] = (r < n) ? x[r * C_IN + (t & (C_IN - 1))] : 0.f;
    }
    __syncthreads();
    int wave = threadIdx.x >> 6, lane = threadIdx.x & 63;
    int i = blockIdx.x * 4 + wave;
    if (i >= n) return;
    float o0 = 0.f, o1 = 0.f;
#pragma unroll
    for (int k4 = 0; k4 < C_IN / 4; k4++) {
        float4 xk = *(const float4*)&xl[wave * C_IN + k4 * 4];
        o0 += xk.x * Wlds[(k4 * 4 + 0) * C_H + lane];
        o1 += xk.y * Wlds[(k4 * 4 + 1) * C_H + lane];
        o0 += xk.z * Wlds[(k4 * 4 + 2) * C_H + lane];
        o1 += xk.w * Wlds[(k4 * 4 + 3) * C_H + lane];
    }
    out[i * C_H + lane] = o0 + o1;
}

// ---------------- fused layer: aggregate(hw) -> relu(+b) -> @Wnext ----------------
// Wave = 4 edge-groups x 16 lanes. Each lane loads a float4 row chunk:
// one dwordx4 per 4 edges, unrolled x2 for MLP.

__global__ __launch_bounds__(256) void layer_kernel(const float* __restrict__ hw,
                                                    const int* __restrict__ rowStart,
                                                    const int* __restrict__ cnt,
                                                    const int2* __restrict__ csr_sw,
                                                    const float* __restrict__ dinv,
                                                    const float* __restrict__ bias,
                                                    const float* __restrict__ Wnext,
                                                    float* __restrict__ out) {
    __shared__ float Wlds[C_H * C_H];  // 16 KB
    __shared__ float hbuf[4][C_H];     // 1 KB
    for (int t = threadIdx.x; t < C_H * C_H; t += 256) Wlds[t] = Wnext[t];

    int wave = threadIdx.x >> 6, lane = threadIdx.x & 63;
    int g = lane >> 4;          // edge sub-group 0..3
    int r = lane & 15;          // channel chunk: channels 4r..4r+3
    int i = blockIdx.x * 4 + wave;   // grid sized exactly: always valid

    int start = rowStart[i];
    int deg = cnt[i];

    float4 acc0 = make_float4(0.f, 0.f, 0.f, 0.f);
    float4 acc1 = make_float4(0.f, 0.f, 0.f, 0.f);

    for (int base = 0; base < deg; base += 8) {
        int ge0 = base + g;
        int ge1 = ge0 + 4;
        int ce0 = (ge0 < deg) ? ge0 : 0;
        int ce1 = (ge1 < deg) ? ge1 : 0;
        int2 sw0 = csr_sw[start + ce0];
        int2 sw1 = csr_sw[start + ce1];
        float w0 = (ge0 < deg) ? __int_as_float(sw0.y) : 0.f;
        float w1 = (ge1 < deg) ? __int_as_float(sw1.y) : 0.f;
        const float4 row0 = *(const float4*)(hw + (size_t)sw0.x * C_H + r * 4);
        const float4 row1 = *(const float4*)(hw + (size_t)sw1.x * C_H + r * 4);
        acc0.x += row0.x * w0; acc0.y += row0.y * w0;
        acc0.z += row0.z * w0; acc0.w += row0.w * w0;
        acc1.x += row1.x * w1; acc1.y += row1.y * w1;
        acc1.z += row1.z * w1; acc1.w += row1.w * w1;
    }
    acc0.x += acc1.x; acc0.y += acc1.y; acc0.z += acc1.z; acc0.w += acc1.w;

    // reduce the 4 edge-groups: butterfly over lane bits 4,5
    acc0.x += __shfl_xor(acc0.x, 16); acc0.y += __shfl_xor(acc0.y, 16);
    acc0.z += __shfl_xor(acc0.z, 16); acc0.w += __shfl_xor(acc0.w, 16);
    acc0.x += __shfl_xor(acc0.x, 32); acc0.y += __shfl_xor(acc0.y, 32);
    acc0.z += __shfl_xor(acc0.z, 32); acc0.w += __shfl_xor(acc0.w, 32);

    // self loop + bias + relu (all groups hold identical sums)
    float di = dinv[i];
    float sl = di * di;
    float4 self4 = *(const float4*)(hw + (size_t)i * C_H + r * 4);
    float4 b4 = *(const float4*)(bias + r * 4);
    float4 h4;
    h4.x = fmaxf(acc0.x + self4.x * sl + b4.x, 0.f);
    h4.y = fmaxf(acc0.y + self4.y * sl + b4.y, 0.f);
    h4.z = fmaxf(acc0.z + self4.z * sl + b4.z, 0.f);
    h4.w = fmaxf(acc0.w + self4.w * sl + b4.w, 0.f);

    if (g == 0) *(float4*)&hbuf[wave][r * 4] = h4;
    __syncthreads();

    // GEMV: out[i][lane] = sum_k h[k] * Wnext[k][lane]
    float o0 = 0.f, o1 = 0.f;
#pragma unroll
    for (int k4 = 0; k4 < C_H / 4; k4++) {
        float4 hk = *(const float4*)&hbuf[wave][k4 * 4];   // broadcast read
        o0 += hk.x * Wlds[(k4 * 4 + 0) * C_H + lane];
        o1 += hk.y * Wlds[(k4 * 4 + 1) * C_H + lane];
        o0 += hk.z * Wlds[(k4 * 4 + 2) * C_H + lane];
        o1 += hk.w * Wlds[(k4 * 4 + 3) * C_H + lane];
    }
    out[(size_t)i * C_H + lane] = o0 + o1;
}

// ---------------- pooling head ----------------

__global__ __launch_bounds__(256) void pool_kernel(const float* __restrict__ hn,
                                                   float* __restrict__ poolbuf) {
    int g = blockIdx.x >> 4;      // graph
    int s = blockIdx.x & 15;      // slice
    int lane = threadIdx.x & 63;
    int rg = threadIdx.x >> 6;    // 0..3
    int stream = s * 4 + rg;      // 0..63
    float acc = 0.f;
    for (int r = stream; r < N_PER_G; r += 64)
        acc += hn[(size_t)(g * N_PER_G + r) * C_H + lane];
    __shared__ float red[4][C_H];
    red[rg][lane] = acc;
    __syncthreads();
    if (rg == 0) {
        float t = red[0][lane] + red[1][lane] + red[2][lane] + red[3][lane];
        atomicAdd(&poolbuf[g * C_H + lane], t);
    }
}

__global__ void poolwp_kernel(const float* __restrict__ poolbuf,
                              const float* __restrict__ Wp,
                              float* __restrict__ poolwp) {
    int g = blockIdx.x, c = threadIdx.x;
    float o = 0.f;
#pragma unroll 8
    for (int k = 0; k < C_H; k++) o += poolbuf[g * C_H + k] * Wp[k * C_H + c];
    poolwp[g * C_H + c] = o;
}

__global__ __launch_bounds__(256) void final_kernel(const float* __restrict__ hn,
                                                    const float* __restrict__ poolwp,
                                                    const float* __restrict__ Wa,
                                                    float* __restrict__ out, int n) {
    int wave = threadIdx.x >> 6, lane = threadIdx.x & 63;
    int i = blockIdx.x * 4 + wave;
    if (i >= n) return;
    int g = i / N_PER_G;
    float v = fmaxf(hn[(size_t)i * C_H + lane], 0.f) * Wa[lane]
            + fmaxf(poolwp[g * C_H + lane], 0.f) * Wa[C_H + lane];
#pragma unroll
    for (int off = 32; off; off >>= 1) v += __shfl_down(v, off);
    if (lane == 0) out[i] = tanhf(v);
}

// ---------------- launch ----------------

extern "C" void kernel_launch(void* const* d_in, const int* in_sizes, int n_in,
                              void* d_out, int out_size, void* d_ws, size_t ws_size,
                              hipStream_t stream) {
    const float* x   = (const float*)d_in[0];
    const int*   ei  = (const int*)d_in[1];
    const float* W0  = (const float*)d_in[2];
    const float* b0  = (const float*)d_in[3];
    const float* Ws  = (const float*)d_in[4];
    const float* bs  = (const float*)d_in[5];
    const float* Wn  = (const float*)d_in[6];
    const float* Wp  = (const float*)d_in[7];
    const float* Wa  = (const float*)d_in[8];
    float* out = (float*)d_out;

    const int* e_src = ei;
    const int* e_dst = ei + N_EDGES;

    size_t off = 0;
    auto alloc = [&](size_t bytes) { size_t o = off; off = (off + bytes + 255) & ~(size_t)255; return o; };
    char* ws = (char*)d_ws;
    int*   cnt      = (int*)  (ws + alloc(N_NODES * 4));
    int*   rowStart = (int*)  (ws + alloc(N_NODES * 4));
    int*   cursor   = (int*)  (ws + alloc(N_NODES * 4));
    float* dinv     = (float*)(ws + alloc(N_NODES * 4));
    int2*  csr_sw   = (int2*) (ws + alloc((size_t)N_EDGES * 8));
    float* bufA     = (float*)(ws + alloc((size_t)N_NODES * C_H * 4));
    float* bufB     = (float*)(ws + alloc((size_t)N_NODES * C_H * 4));
    float* poolbuf  = (float*)(ws + alloc(N_GRAPH * C_H * 4));
    float* poolwp   = (float*)(ws + alloc(N_GRAPH * C_H * 4));

    hipMemsetAsync(cnt, 0, N_NODES * 4, stream);
    hipMemsetAsync(poolbuf, 0, N_GRAPH * C_H * 4, stream);

    const int EB = (N_EDGES + 255) / 256;
    count_kernel<<<EB, 256, 0, stream>>>(e_dst, cnt, N_EDGES);
    scan_kernel<<<1, 1024, 0, stream>>>(cnt, rowStart, cursor, dinv, N_NODES);
    scatter_kernel<<<EB, 256, 0, stream>>>(e_src, e_dst, cursor, dinv, csr_sw, N_EDGES);

    const int NB = N_NODES / 4;   // 12500, exact
    gemm0_kernel<<<NB, 256, 0, stream>>>(x, W0, bufA, N_NODES);  // hw0 = x @ W0

    for (int k = 0; k < N_LAYER; k++) {
        const float* hin  = (k & 1) ? bufB : bufA;
        float*       hout = (k & 1) ? bufA : bufB;
        const float* bias  = (k == 0) ? b0 : (bs + (k - 1) * C_H);
        const float* Wnext = (k < N_LAYER - 1) ? (Ws + k * C_H * C_H) : Wn;
        layer_kernel<<<NB, 256, 0, stream>>>(hin, rowStart, cnt, csr_sw,
                                             dinv, bias, Wnext, hout);
    }
    const float* hn = bufB;   // layer 8 output

    pool_kernel<<<N_GRAPH * 16, 256, 0, stream>>>(hn, poolbuf);
    poolwp_kernel<<<N_GRAPH, C_H, 0, stream>>>(poolbuf, Wp, poolwp);
    final_kernel<<<NB, 256, 0, stream>>>(hn, poolwp, Wa, out, N_NODES);
}

// Round 3
// 640.966 us; speedup vs baseline: 1.6472x; 1.2203x over previous
//
#include <hip/hip_runtime.h>
#include <hip/hip_bf16.h>

#define N_NODES 50000
#define N_EDGES 800000
#define C_IN    128
#define C_H     64
#define N_LAYER 9
#define N_GRAPH 10
#define N_PER_G 5000
#define NSB     ((N_NODES + 255) / 256)   // 196 scan blocks

// ---------------- CSR build ----------------

__global__ void count_kernel(const int* __restrict__ dst, int* __restrict__ cnt, int e) {
    int i = blockIdx.x * blockDim.x + threadIdx.x;
    if (i < e) atomicAdd(&cnt[dst[i]], 1);
}

// per-block sums of cnt
__global__ __launch_bounds__(256) void bsum_kernel(const int* __restrict__ cnt,
                                                   int* __restrict__ bsum) {
    int i = blockIdx.x * 256 + threadIdx.x;
    int v = (i < N_NODES) ? cnt[i] : 0;
#pragma unroll
    for (int off = 32; off; off >>= 1) v += __shfl_down(v, off);
    __shared__ int s[4];
    if ((threadIdx.x & 63) == 0) s[threadIdx.x >> 6] = v;
    __syncthreads();
    if (threadIdx.x == 0) bsum[blockIdx.x] = s[0] + s[1] + s[2] + s[3];
}

// per-block: global offset from bsum[0..b), in-block exclusive scan, emit CSR row starts
__global__ __launch_bounds__(256) void scan2_kernel(const int* __restrict__ cnt,
                                                    const int* __restrict__ bsum,
                                                    int* __restrict__ rowStart,
                                                    int* __restrict__ cursor,
                                                    float* __restrict__ dinv) {
    int b = blockIdx.x, t = threadIdx.x;

    // block offset = sum of bsum[0..b)   (b <= 195 < 256: one value per thread)
    int v = (t < b) ? bsum[t] : 0;
#pragma unroll
    for (int off = 32; off; off >>= 1) v += __shfl_down(v, off);
    __shared__ int sw[4];
    __shared__ int soff;
    if ((t & 63) == 0) sw[t >> 6] = v;
    __syncthreads();
    if (t == 0) soff = sw[0] + sw[1] + sw[2] + sw[3];

    // in-block Hillis-Steele inclusive scan of cnt chunk
    int i = b * 256 + t;
    int c = (i < N_NODES) ? cnt[i] : 0;
    __shared__ int sd[256];
    sd[t] = c;
    __syncthreads();
#pragma unroll
    for (int off = 1; off < 256; off <<= 1) {
        int x = sd[t];
        int y = (t >= off) ? sd[t - off] : 0;
        __syncthreads();
        sd[t] = x + y;
        __syncthreads();
    }
    if (i < N_NODES) {
        int rs = soff + sd[t] - c;   // exclusive prefix + block offset
        rowStart[i] = rs;
        cursor[i] = rs;
        dinv[i] = rsqrtf((float)c + 1.0f);
    }
}

// pack (src, weight) into int2 per edge
__global__ void scatter_kernel(const int* __restrict__ src, const int* __restrict__ dst,
                               int* __restrict__ cursor, const float* __restrict__ dinv,
                               int2* __restrict__ csr_sw, int e) {
    int i = blockIdx.x * blockDim.x + threadIdx.x;
    if (i < e) {
        int d = dst[i], s = src[i];
        int p = atomicAdd(&cursor[d], 1);
        float w = dinv[s] * dinv[d];
        csr_sw[p] = make_int2(s, __float_as_int(w));
    }
}

// ---------------- layer 0 input GEMM: hw0 = x @ W0  (K=128) ----------------

__global__ __launch_bounds__(256) void gemm0_kernel(const float* __restrict__ x,
                                                    const float* __restrict__ W0,
                                                    float* __restrict__ out, int n) {
    __shared__ float Wlds[C_IN * C_H];   // 32 KB
    __shared__ float xl[4 * C_IN];       // 2 KB
    for (int t = threadIdx.x; t < C_IN * C_H; t += 256) Wlds[t] = W0[t];
    for (int t = threadIdx.x; t < 4 * C_IN; t += 256) {
        int r = blockIdx.x * 4 + t / C_IN;
        xl[t] = (r < n) ? x[r * C_IN + (t & (C_IN - 1))] : 0.f;
    }
    __syncthreads();
    int wave = threadIdx.x >> 6, lane = threadIdx.x & 63;
    int i = blockIdx.x * 4 + wave;
    if (i >= n) return;
    float o0 = 0.f, o1 = 0.f;
#pragma unroll
    for (int k4 = 0; k4 < C_IN / 4; k4++) {
        float4 xk = *(const float4*)&xl[wave * C_IN + k4 * 4];
        o0 += xk.x * Wlds[(k4 * 4 + 0) * C_H + lane];
        o1 += xk.y * Wlds[(k4 * 4 + 1) * C_H + lane];
        o0 += xk.z * Wlds[(k4 * 4 + 2) * C_H + lane];
        o1 += xk.w * Wlds[(k4 * 4 + 3) * C_H + lane];
    }
    out[i * C_H + lane] = o0 + o1;
}

// ---------------- fused layer: aggregate(hw) -> relu(+b) -> @Wnext ----------------

__global__ __launch_bounds__(256) void layer_kernel(const float* __restrict__ hw,
                                                    const int* __restrict__ rowStart,
                                                    const int* __restrict__ cnt,
                                                    const int2* __restrict__ csr_sw,
                                                    const float* __restrict__ dinv,
                                                    const float* __restrict__ bias,
                                                    const float* __restrict__ Wnext,
                                                    float* __restrict__ out) {
    __shared__ float Wlds[C_H * C_H];  // 16 KB
    __shared__ float hbuf[4][C_H];     // 1 KB
    for (int t = threadIdx.x; t < C_H * C_H; t += 256) Wlds[t] = Wnext[t];

    int wave = threadIdx.x >> 6, lane = threadIdx.x & 63;
    int g = lane >> 4;          // edge sub-group 0..3
    int r = lane & 15;          // channel chunk: channels 4r..4r+3
    int i = blockIdx.x * 4 + wave;   // grid sized exactly: always valid

    int start = rowStart[i];
    int deg = cnt[i];

    float4 acc0 = make_float4(0.f, 0.f, 0.f, 0.f);
    float4 acc1 = make_float4(0.f, 0.f, 0.f, 0.f);

    for (int base = 0; base < deg; base += 8) {
        int ge0 = base + g;
        int ge1 = ge0 + 4;
        int ce0 = (ge0 < deg) ? ge0 : 0;
        int ce1 = (ge1 < deg) ? ge1 : 0;
        int2 sw0 = csr_sw[start + ce0];
        int2 sw1 = csr_sw[start + ce1];
        float w0 = (ge0 < deg) ? __int_as_float(sw0.y) : 0.f;
        float w1 = (ge1 < deg) ? __int_as_float(sw1.y) : 0.f;
        const float4 row0 = *(const float4*)(hw + (size_t)sw0.x * C_H + r * 4);
        const float4 row1 = *(const float4*)(hw + (size_t)sw1.x * C_H + r * 4);
        acc0.x += row0.x * w0; acc0.y += row0.y * w0;
        acc0.z += row0.z * w0; acc0.w += row0.w * w0;
        acc1.x += row1.x * w1; acc1.y += row1.y * w1;
        acc1.z += row1.z * w1; acc1.w += row1.w * w1;
    }
    acc0.x += acc1.x; acc0.y += acc1.y; acc0.z += acc1.z; acc0.w += acc1.w;

    acc0.x += __shfl_xor(acc0.x, 16); acc0.y += __shfl_xor(acc0.y, 16);
    acc0.z += __shfl_xor(acc0.z, 16); acc0.w += __shfl_xor(acc0.w, 16);
    acc0.x += __shfl_xor(acc0.x, 32); acc0.y += __shfl_xor(acc0.y, 32);
    acc0.z += __shfl_xor(acc0.z, 32); acc0.w += __shfl_xor(acc0.w, 32);

    float di = dinv[i];
    float sl = di * di;
    float4 self4 = *(const float4*)(hw + (size_t)i * C_H + r * 4);
    float4 b4 = *(const float4*)(bias + r * 4);
    float4 h4;
    h4.x = fmaxf(acc0.x + self4.x * sl + b4.x, 0.f);
    h4.y = fmaxf(acc0.y + self4.y * sl + b4.y, 0.f);
    h4.z = fmaxf(acc0.z + self4.z * sl + b4.z, 0.f);
    h4.w = fmaxf(acc0.w + self4.w * sl + b4.w, 0.f);

    if (g == 0) *(float4*)&hbuf[wave][r * 4] = h4;
    __syncthreads();

    float o0 = 0.f, o1 = 0.f;
#pragma unroll
    for (int k4 = 0; k4 < C_H / 4; k4++) {
        float4 hk = *(const float4*)&hbuf[wave][k4 * 4];   // broadcast read
        o0 += hk.x * Wlds[(k4 * 4 + 0) * C_H + lane];
        o1 += hk.y * Wlds[(k4 * 4 + 1) * C_H + lane];
        o0 += hk.z * Wlds[(k4 * 4 + 2) * C_H + lane];
        o1 += hk.w * Wlds[(k4 * 4 + 3) * C_H + lane];
    }
    out[(size_t)i * C_H + lane] = o0 + o1;
}

// ---------------- pooling head ----------------

__global__ __launch_bounds__(256) void pool_kernel(const float* __restrict__ hn,
                                                   float* __restrict__ poolbuf) {
    int g = blockIdx.x >> 4;
    int s = blockIdx.x & 15;
    int lane = threadIdx.x & 63;
    int rg = threadIdx.x >> 6;
    int stream = s * 4 + rg;
    float acc = 0.f;
    for (int r = stream; r < N_PER_G; r += 64)
        acc += hn[(size_t)(g * N_PER_G + r) * C_H + lane];
    __shared__ float red[4][C_H];
    red[rg][lane] = acc;
    __syncthreads();
    if (rg == 0) {
        float t = red[0][lane] + red[1][lane] + red[2][lane] + red[3][lane];
        atomicAdd(&poolbuf[g * C_H + lane], t);
    }
}

__global__ void poolwp_kernel(const float* __restrict__ poolbuf,
                              const float* __restrict__ Wp,
                              float* __restrict__ poolwp) {
    int g = blockIdx.x, c = threadIdx.x;
    float o = 0.f;
#pragma unroll 8
    for (int k = 0; k < C_H; k++) o += poolbuf[g * C_H + k] * Wp[k * C_H + c];
    poolwp[g * C_H + c] = o;
}

__global__ __launch_bounds__(256) void final_kernel(const float* __restrict__ hn,
                                                    const float* __restrict__ poolwp,
                                                    const float* __restrict__ Wa,
                                                    float* __restrict__ out, int n) {
    int wave = threadIdx.x >> 6, lane = threadIdx.x & 63;
    int i = blockIdx.x * 4 + wave;
    if (i >= n) return;
    int g = i / N_PER_G;
    float v = fmaxf(hn[(size_t)i * C_H + lane], 0.f) * Wa[lane]
            + fmaxf(poolwp[g * C_H + lane], 0.f) * Wa[C_H + lane];
#pragma unroll
    for (int off = 32; off; off >>= 1) v += __shfl_down(v, off);
    if (lane == 0) out[i] = tanhf(v);
}

// ---------------- launch ----------------

extern "C" void kernel_launch(void* const* d_in, const int* in_sizes, int n_in,
                              void* d_out, int out_size, void* d_ws, size_t ws_size,
                              hipStream_t stream) {
    const float* x   = (const float*)d_in[0];
    const int*   ei  = (const int*)d_in[1];
    const float* W0  = (const float*)d_in[2];
    const float* b0  = (const float*)d_in[3];
    const float* Ws  = (const float*)d_in[4];
    const float* bs  = (const float*)d_in[5];
    const float* Wn  = (const float*)d_in[6];
    const float* Wp  = (const float*)d_in[7];
    const float* Wa  = (const float*)d_in[8];
    float* out = (float*)d_out;

    const int* e_src = ei;
    const int* e_dst = ei + N_EDGES;

    size_t off = 0;
    auto alloc = [&](size_t bytes) { size_t o = off; off = (off + bytes + 255) & ~(size_t)255; return o; };
    char* ws = (char*)d_ws;
    int*   cnt      = (int*)  (ws + alloc(N_NODES * 4));
    int*   rowStart = (int*)  (ws + alloc(N_NODES * 4));
    int*   cursor   = (int*)  (ws + alloc(N_NODES * 4));
    float* dinv     = (float*)(ws + alloc(N_NODES * 4));
    int*   bsum     = (int*)  (ws + alloc(NSB * 4));
    int2*  csr_sw   = (int2*) (ws + alloc((size_t)N_EDGES * 8));
    float* bufA     = (float*)(ws + alloc((size_t)N_NODES * C_H * 4));
    float* bufB     = (float*)(ws + alloc((size_t)N_NODES * C_H * 4));
    float* poolbuf  = (float*)(ws + alloc(N_GRAPH * C_H * 4));
    float* poolwp   = (float*)(ws + alloc(N_GRAPH * C_H * 4));

    hipMemsetAsync(cnt, 0, N_NODES * 4, stream);
    hipMemsetAsync(poolbuf, 0, N_GRAPH * C_H * 4, stream);

    const int EB = (N_EDGES + 255) / 256;
    count_kernel<<<EB, 256, 0, stream>>>(e_dst, cnt, N_EDGES);
    bsum_kernel<<<NSB, 256, 0, stream>>>(cnt, bsum);
    scan2_kernel<<<NSB, 256, 0, stream>>>(cnt, bsum, rowStart, cursor, dinv);
    scatter_kernel<<<EB, 256, 0, stream>>>(e_src, e_dst, cursor, dinv, csr_sw, N_EDGES);

    const int NB = N_NODES / 4;   // 12500, exact
    gemm0_kernel<<<NB, 256, 0, stream>>>(x, W0, bufA, N_NODES);  // hw0 = x @ W0

    for (int k = 0; k < N_LAYER; k++) {
        const float* hin  = (k & 1) ? bufB : bufA;
        float*       hout = (k & 1) ? bufA : bufB;
        const float* bias  = (k == 0) ? b0 : (bs + (k - 1) * C_H);
        const float* Wnext = (k < N_LAYER - 1) ? (Ws + k * C_H * C_H) : Wn;
        layer_kernel<<<NB, 256, 0, stream>>>(hin, rowStart, cnt, csr_sw,
                                             dinv, bias, Wnext, hout);
    }
    const float* hn = bufB;   // layer 8 output

    pool_kernel<<<N_GRAPH * 16, 256, 0, stream>>>(hn, poolbuf);
    poolwp_kernel<<<N_GRAPH, C_H, 0, stream>>>(poolbuf, Wp, poolwp);
    final_kernel<<<NB, 256, 0, stream>>>(hn, poolwp, Wa, out, N_NODES);
}

// Round 4
// 615.311 us; speedup vs baseline: 1.7159x; 1.0417x over previous
//
#include <hip/hip_runtime.h>
#include <hip/hip_bf16.h>

#define N_NODES 50000
#define N_EDGES 800000
#define C_IN    128
#define C_H     64
#define N_LAYER 9
#define N_GRAPH 10
#define N_PER_G 5000
#define NSB     ((N_NODES + 255) / 256)   // 196 scan blocks
#define NPB     16                         // nodes per block in layer kernel
#define RPB     16                         // rows per block in gemm0

// ---------------- CSR build ----------------

__global__ void count_kernel(const int* __restrict__ dst, int* __restrict__ cnt, int e) {
    int i = blockIdx.x * blockDim.x + threadIdx.x;
    if (i < e) atomicAdd(&cnt[dst[i]], 1);
}

__global__ __launch_bounds__(256) void bsum_kernel(const int* __restrict__ cnt,
                                                   int* __restrict__ bsum) {
    int i = blockIdx.x * 256 + threadIdx.x;
    int v = (i < N_NODES) ? cnt[i] : 0;
#pragma unroll
    for (int off = 32; off; off >>= 1) v += __shfl_down(v, off);
    __shared__ int s[4];
    if ((threadIdx.x & 63) == 0) s[threadIdx.x >> 6] = v;
    __syncthreads();
    if (threadIdx.x == 0) bsum[blockIdx.x] = s[0] + s[1] + s[2] + s[3];
}

__global__ __launch_bounds__(256) void scan2_kernel(const int* __restrict__ cnt,
                                                    const int* __restrict__ bsum,
                                                    int* __restrict__ rowStart,
                                                    int* __restrict__ cursor,
                                                    float* __restrict__ dinv) {
    int b = blockIdx.x, t = threadIdx.x;
    int v = (t < b) ? bsum[t] : 0;
#pragma unroll
    for (int off = 32; off; off >>= 1) v += __shfl_down(v, off);
    __shared__ int sw[4];
    __shared__ int soff;
    if ((t & 63) == 0) sw[t >> 6] = v;
    __syncthreads();
    if (t == 0) soff = sw[0] + sw[1] + sw[2] + sw[3];

    int i = b * 256 + t;
    int c = (i < N_NODES) ? cnt[i] : 0;
    __shared__ int sd[256];
    sd[t] = c;
    __syncthreads();
#pragma unroll
    for (int off = 1; off < 256; off <<= 1) {
        int x = sd[t];
        int y = (t >= off) ? sd[t - off] : 0;
        __syncthreads();
        sd[t] = x + y;
        __syncthreads();
    }
    if (i < N_NODES) {
        int rs = soff + sd[t] - c;
        rowStart[i] = rs;
        cursor[i] = rs;
        dinv[i] = rsqrtf((float)c + 1.0f);
    }
}

__global__ void scatter_kernel(const int* __restrict__ src, const int* __restrict__ dst,
                               int* __restrict__ cursor, const float* __restrict__ dinv,
                               int2* __restrict__ csr_sw, int e) {
    int i = blockIdx.x * blockDim.x + threadIdx.x;
    if (i < e) {
        int d = dst[i], s = src[i];
        int p = atomicAdd(&cursor[d], 1);
        float w = dinv[s] * dinv[d];
        csr_sw[p] = make_int2(s, __float_as_int(w));
    }
}

// ---------------- layer 0 input GEMM: hw0 = x @ W0  (K=128) ----------------
// 16 rows per block; W0 (32 KB) + xl (8 KB) in LDS; 4 rows per wave.

__global__ __launch_bounds__(256) void gemm0_kernel(const float* __restrict__ x,
                                                    const float* __restrict__ W0,
                                                    float* __restrict__ out) {
    __shared__ float Wlds[C_IN * C_H];   // 32 KB
    __shared__ float xl[RPB * C_IN];     // 8 KB
    for (int t = threadIdx.x; t < (C_IN * C_H) / 4; t += 256)
        *(float4*)&Wlds[t * 4] = *(const float4*)&W0[t * 4];
    {
        const float4* xs = (const float4*)(x + (size_t)blockIdx.x * RPB * C_IN);
        float4* xd = (float4*)xl;
        for (int t = threadIdx.x; t < (RPB * C_IN) / 4; t += 256) xd[t] = xs[t];
    }
    __syncthreads();
    int wave = threadIdx.x >> 6, lane = threadIdx.x & 63;
#pragma unroll
    for (int nn = 0; nn < 4; nn++) {
        int row = wave * 4 + nn;
        float o0 = 0.f, o1 = 0.f;
#pragma unroll
        for (int k4 = 0; k4 < C_IN / 4; k4++) {
            float4 xk = *(const float4*)&xl[row * C_IN + k4 * 4];
            o0 += xk.x * Wlds[(k4 * 4 + 0) * C_H + lane];
            o1 += xk.y * Wlds[(k4 * 4 + 1) * C_H + lane];
            o0 += xk.z * Wlds[(k4 * 4 + 2) * C_H + lane];
            o1 += xk.w * Wlds[(k4 * 4 + 3) * C_H + lane];
        }
        out[((size_t)blockIdx.x * RPB + row) * C_H + lane] = o0 + o1;
    }
}

// ---------------- fused layer: aggregate(hw) -> relu(+b) -> @Wnext ----------------
// 16 nodes per block (4 per wave). Gather: 4 edge-groups x 16 lanes, 16 edges
// per iteration = 4 independent float4 row loads in flight per wave.

__global__ __launch_bounds__(256) void layer_kernel(const float* __restrict__ hw,
                                                    const int* __restrict__ rowStart,
                                                    const int* __restrict__ cnt,
                                                    const int2* __restrict__ csr_sw,
                                                    const float* __restrict__ dinv,
                                                    const float* __restrict__ bias,
                                                    const float* __restrict__ Wnext,
                                                    float* __restrict__ out) {
    __shared__ float Wlds[C_H * C_H];   // 16 KB
    __shared__ float hbuf[NPB][C_H];    // 4 KB
    for (int t = threadIdx.x; t < (C_H * C_H) / 4; t += 256)
        *(float4*)&Wlds[t * 4] = *(const float4*)&Wnext[t * 4];

    int wave = threadIdx.x >> 6, lane = threadIdx.x & 63;
    int g = lane >> 4;          // edge sub-group 0..3
    int r = lane & 15;          // channel chunk: channels 4r..4r+3
    int ibase = blockIdx.x * NPB + wave * 4;

    float4 b4 = *(const float4*)(bias + r * 4);

#pragma unroll
    for (int nn = 0; nn < 4; nn++) {
        int i = ibase + nn;
        int start = rowStart[i];
        int deg = cnt[i];

        float4 a0 = make_float4(0.f, 0.f, 0.f, 0.f);
        float4 a1 = make_float4(0.f, 0.f, 0.f, 0.f);
        float4 a2 = make_float4(0.f, 0.f, 0.f, 0.f);
        float4 a3 = make_float4(0.f, 0.f, 0.f, 0.f);

        for (int base = 0; base < deg; base += 16) {
            int ge0 = base + g, ge1 = ge0 + 4, ge2 = ge0 + 8, ge3 = ge0 + 12;
            int2 sw0 = csr_sw[start + ((ge0 < deg) ? ge0 : 0)];
            int2 sw1 = csr_sw[start + ((ge1 < deg) ? ge1 : 0)];
            int2 sw2 = csr_sw[start + ((ge2 < deg) ? ge2 : 0)];
            int2 sw3 = csr_sw[start + ((ge3 < deg) ? ge3 : 0)];
            float w0 = (ge0 < deg) ? __int_as_float(sw0.y) : 0.f;
            float w1 = (ge1 < deg) ? __int_as_float(sw1.y) : 0.f;
            float w2 = (ge2 < deg) ? __int_as_float(sw2.y) : 0.f;
            float w3 = (ge3 < deg) ? __int_as_float(sw3.y) : 0.f;
            const float4 row0 = *(const float4*)(hw + (size_t)sw0.x * C_H + r * 4);
            const float4 row1 = *(const float4*)(hw + (size_t)sw1.x * C_H + r * 4);
            const float4 row2 = *(const float4*)(hw + (size_t)sw2.x * C_H + r * 4);
            const float4 row3 = *(const float4*)(hw + (size_t)sw3.x * C_H + r * 4);
            a0.x += row0.x * w0; a0.y += row0.y * w0; a0.z += row0.z * w0; a0.w += row0.w * w0;
            a1.x += row1.x * w1; a1.y += row1.y * w1; a1.z += row1.z * w1; a1.w += row1.w * w1;
            a2.x += row2.x * w2; a2.y += row2.y * w2; a2.z += row2.z * w2; a2.w += row2.w * w2;
            a3.x += row3.x * w3; a3.y += row3.y * w3; a3.z += row3.z * w3; a3.w += row3.w * w3;
        }
        a0.x += a1.x + a2.x + a3.x;
        a0.y += a1.y + a2.y + a3.y;
        a0.z += a1.z + a2.z + a3.z;
        a0.w += a1.w + a2.w + a3.w;

        a0.x += __shfl_xor(a0.x, 16); a0.y += __shfl_xor(a0.y, 16);
        a0.z += __shfl_xor(a0.z, 16); a0.w += __shfl_xor(a0.w, 16);
        a0.x += __shfl_xor(a0.x, 32); a0.y += __shfl_xor(a0.y, 32);
        a0.z += __shfl_xor(a0.z, 32); a0.w += __shfl_xor(a0.w, 32);

        float di = dinv[i];
        float sl = di * di;
        float4 self4 = *(const float4*)(hw + (size_t)i * C_H + r * 4);
        if (g == 0) {
            float4 h4;
            h4.x = fmaxf(a0.x + self4.x * sl + b4.x, 0.f);
            h4.y = fmaxf(a0.y + self4.y * sl + b4.y, 0.f);
            h4.z = fmaxf(a0.z + self4.z * sl + b4.z, 0.f);
            h4.w = fmaxf(a0.w + self4.w * sl + b4.w, 0.f);
            *(float4*)&hbuf[wave * 4 + nn][r * 4] = h4;
        }
    }
    __syncthreads();   // Wlds fill (from all threads) + hbuf visibility

    // GEMV: out[i][lane] = sum_k h[k] * Wnext[k][lane], 4 nodes per wave
#pragma unroll
    for (int nn = 0; nn < 4; nn++) {
        float o0 = 0.f, o1 = 0.f;
#pragma unroll
        for (int k4 = 0; k4 < C_H / 4; k4++) {
            float4 hk = *(const float4*)&hbuf[wave * 4 + nn][k4 * 4];  // broadcast
            o0 += hk.x * Wlds[(k4 * 4 + 0) * C_H + lane];
            o1 += hk.y * Wlds[(k4 * 4 + 1) * C_H + lane];
            o0 += hk.z * Wlds[(k4 * 4 + 2) * C_H + lane];
            o1 += hk.w * Wlds[(k4 * 4 + 3) * C_H + lane];
        }
        out[(size_t)(ibase + nn) * C_H + lane] = o0 + o1;
    }
}

// ---------------- pooling head ----------------

__global__ __launch_bounds__(256) void pool_kernel(const float* __restrict__ hn,
                                                   float* __restrict__ poolbuf) {
    int g = blockIdx.x >> 4;
    int s = blockIdx.x & 15;
    int lane = threadIdx.x & 63;
    int rg = threadIdx.x >> 6;
    int stream = s * 4 + rg;
    float acc = 0.f;
    for (int r = stream; r < N_PER_G; r += 64)
        acc += hn[(size_t)(g * N_PER_G + r) * C_H + lane];
    __shared__ float red[4][C_H];
    red[rg][lane] = acc;
    __syncthreads();
    if (rg == 0) {
        float t = red[0][lane] + red[1][lane] + red[2][lane] + red[3][lane];
        atomicAdd(&poolbuf[g * C_H + lane], t);
    }
}

__global__ void poolwp_kernel(const float* __restrict__ poolbuf,
                              const float* __restrict__ Wp,
                              float* __restrict__ poolwp) {
    int g = blockIdx.x, c = threadIdx.x;
    float o = 0.f;
#pragma unroll 8
    for (int k = 0; k < C_H; k++) o += poolbuf[g * C_H + k] * Wp[k * C_H + c];
    poolwp[g * C_H + c] = o;
}

__global__ __launch_bounds__(256) void final_kernel(const float* __restrict__ hn,
                                                    const float* __restrict__ poolwp,
                                                    const float* __restrict__ Wa,
                                                    float* __restrict__ out, int n) {
    int wave = threadIdx.x >> 6, lane = threadIdx.x & 63;
    int i = blockIdx.x * 4 + wave;
    if (i >= n) return;
    int g = i / N_PER_G;
    float v = fmaxf(hn[(size_t)i * C_H + lane], 0.f) * Wa[lane]
            + fmaxf(poolwp[g * C_H + lane], 0.f) * Wa[C_H + lane];
#pragma unroll
    for (int off = 32; off; off >>= 1) v += __shfl_down(v, off);
    if (lane == 0) out[i] = tanhf(v);
}

// ---------------- launch ----------------

extern "C" void kernel_launch(void* const* d_in, const int* in_sizes, int n_in,
                              void* d_out, int out_size, void* d_ws, size_t ws_size,
                              hipStream_t stream) {
    const float* x   = (const float*)d_in[0];
    const int*   ei  = (const int*)d_in[1];
    const float* W0  = (const float*)d_in[2];
    const float* b0  = (const float*)d_in[3];
    const float* Ws  = (const float*)d_in[4];
    const float* bs  = (const float*)d_in[5];
    const float* Wn  = (const float*)d_in[6];
    const float* Wp  = (const float*)d_in[7];
    const float* Wa  = (const float*)d_in[8];
    float* out = (float*)d_out;

    const int* e_src = ei;
    const int* e_dst = ei + N_EDGES;

    size_t off = 0;
    auto alloc = [&](size_t bytes) { size_t o = off; off = (off + bytes + 255) & ~(size_t)255; return o; };
    char* ws = (char*)d_ws;
    int*   cnt      = (int*)  (ws + alloc(N_NODES * 4));
    int*   rowStart = (int*)  (ws + alloc(N_NODES * 4));
    int*   cursor   = (int*)  (ws + alloc(N_NODES * 4));
    float* dinv     = (float*)(ws + alloc(N_NODES * 4));
    int*   bsum     = (int*)  (ws + alloc(NSB * 4));
    int2*  csr_sw   = (int2*) (ws + alloc((size_t)N_EDGES * 8));
    float* bufA     = (float*)(ws + alloc((size_t)N_NODES * C_H * 4));
    float* bufB     = (float*)(ws + alloc((size_t)N_NODES * C_H * 4));
    float* poolbuf  = (float*)(ws + alloc(N_GRAPH * C_H * 4));
    float* poolwp   = (float*)(ws + alloc(N_GRAPH * C_H * 4));

    hipMemsetAsync(cnt, 0, N_NODES * 4, stream);
    hipMemsetAsync(poolbuf, 0, N_GRAPH * C_H * 4, stream);

    const int EB = (N_EDGES + 255) / 256;
    count_kernel<<<EB, 256, 0, stream>>>(e_dst, cnt, N_EDGES);
    bsum_kernel<<<NSB, 256, 0, stream>>>(cnt, bsum);
    scan2_kernel<<<NSB, 256, 0, stream>>>(cnt, bsum, rowStart, cursor, dinv);
    scatter_kernel<<<EB, 256, 0, stream>>>(e_src, e_dst, cursor, dinv, csr_sw, N_EDGES);

    gemm0_kernel<<<N_NODES / RPB, 256, 0, stream>>>(x, W0, bufA);  // 3125 blocks

    const int LB = N_NODES / NPB;   // 3125, exact
    for (int k = 0; k < N_LAYER; k++) {
        const float* hin  = (k & 1) ? bufB : bufA;
        float*       hout = (k & 1) ? bufA : bufB;
        const float* bias  = (k == 0) ? b0 : (bs + (k - 1) * C_H);
        const float* Wnext = (k < N_LAYER - 1) ? (Ws + k * C_H * C_H) : Wn;
        layer_kernel<<<LB, 256, 0, stream>>>(hin, rowStart, cnt, csr_sw,
                                             dinv, bias, Wnext, hout);
    }
    const float* hn = bufB;   // layer 8 output

    pool_kernel<<<N_GRAPH * 16, 256, 0, stream>>>(hn, poolbuf);
    poolwp_kernel<<<N_GRAPH, C_H, 0, stream>>>(poolbuf, Wp, poolwp);
    final_kernel<<<N_NODES / 4, 256, 0, stream>>>(hn, poolwp, Wa, out, N_NODES);
}

// Round 5
// 544.916 us; speedup vs baseline: 1.9376x; 1.1292x over previous
//
#include <hip/hip_runtime.h>
#include <hip/hip_bf16.h>

#define N_NODES 50000
#define N_EDGES 800000
#define C_IN    128
#define C_H     64
#define C_HU    32                         // u32 words per bf16 row
#define N_LAYER 9
#define N_GRAPH 10
#define N_PER_G 5000
#define NSB     ((N_NODES + 255) / 256)    // 196 scan blocks
#define NPB     16                         // nodes per block in layer kernel
#define RPB     16                         // rows per block in gemm0

typedef unsigned int  u32;
typedef unsigned short u16;

__device__ __forceinline__ float bflo(u32 u) { return __uint_as_float(u << 16); }
__device__ __forceinline__ float bfhi(u32 u) { return __uint_as_float(u & 0xffff0000u); }
__device__ __forceinline__ u16 f2bf(float f) {            // RNE f32 -> bf16
    u32 u = __float_as_uint(f);
    u32 r = u + 0x7fffu + ((u >> 16) & 1u);
    return (u16)(r >> 16);
}
__device__ __forceinline__ void fma8(float* acc, uint4 v, float w) {
    acc[0] += bflo(v.x) * w; acc[1] += bfhi(v.x) * w;
    acc[2] += bflo(v.y) * w; acc[3] += bfhi(v.y) * w;
    acc[4] += bflo(v.z) * w; acc[5] += bfhi(v.z) * w;
    acc[6] += bflo(v.w) * w; acc[7] += bfhi(v.w) * w;
}

// ---------------- CSR build ----------------

__global__ void count_kernel(const int* __restrict__ dst, int* __restrict__ cnt, int e) {
    int i = blockIdx.x * blockDim.x + threadIdx.x;
    if (i < e) atomicAdd(&cnt[dst[i]], 1);
}

__global__ __launch_bounds__(256) void bsum_kernel(const int* __restrict__ cnt,
                                                   int* __restrict__ bsum) {
    int i = blockIdx.x * 256 + threadIdx.x;
    int v = (i < N_NODES) ? cnt[i] : 0;
#pragma unroll
    for (int off = 32; off; off >>= 1) v += __shfl_down(v, off);
    __shared__ int s[4];
    if ((threadIdx.x & 63) == 0) s[threadIdx.x >> 6] = v;
    __syncthreads();
    if (threadIdx.x == 0) bsum[blockIdx.x] = s[0] + s[1] + s[2] + s[3];
}

__global__ __launch_bounds__(256) void scan2_kernel(const int* __restrict__ cnt,
                                                    const int* __restrict__ bsum,
                                                    int* __restrict__ rowStart,
                                                    int* __restrict__ cursor,
                                                    float* __restrict__ dinv) {
    int b = blockIdx.x, t = threadIdx.x;
    int v = (t < b) ? bsum[t] : 0;
#pragma unroll
    for (int off = 32; off; off >>= 1) v += __shfl_down(v, off);
    __shared__ int sw[4];
    __shared__ int soff;
    if ((t & 63) == 0) sw[t >> 6] = v;
    __syncthreads();
    if (t == 0) soff = sw[0] + sw[1] + sw[2] + sw[3];

    int i = b * 256 + t;
    int c = (i < N_NODES) ? cnt[i] : 0;
    __shared__ int sd[256];
    sd[t] = c;
    __syncthreads();
#pragma unroll
    for (int off = 1; off < 256; off <<= 1) {
        int x = sd[t];
        int y = (t >= off) ? sd[t - off] : 0;
        __syncthreads();
        sd[t] = x + y;
        __syncthreads();
    }
    if (i < N_NODES) {
        int rs = soff + sd[t] - c;
        rowStart[i] = rs;
        cursor[i] = rs;
        dinv[i] = rsqrtf((float)c + 1.0f);
    }
}

__global__ void scatter_kernel(const int* __restrict__ src, const int* __restrict__ dst,
                               int* __restrict__ cursor, const float* __restrict__ dinv,
                               int2* __restrict__ csr_sw, int e) {
    int i = blockIdx.x * blockDim.x + threadIdx.x;
    if (i < e) {
        int d = dst[i], s = src[i];
        int p = atomicAdd(&cursor[d], 1);
        float w = dinv[s] * dinv[d];
        csr_sw[p] = make_int2(s, __float_as_int(w));
    }
}

// ---------------- layer 0 input GEMM: hw0 = x @ W0 (K=128), bf16 out ----------------

__global__ __launch_bounds__(256) void gemm0_kernel(const float* __restrict__ x,
                                                    const float* __restrict__ W0,
                                                    u16* __restrict__ out) {
    __shared__ float Wlds[C_IN * C_H];   // 32 KB
    __shared__ float xl[RPB * C_IN];     // 8 KB
    for (int t = threadIdx.x; t < (C_IN * C_H) / 4; t += 256)
        *(float4*)&Wlds[t * 4] = *(const float4*)&W0[t * 4];
    {
        const float4* xs = (const float4*)(x + (size_t)blockIdx.x * RPB * C_IN);
        float4* xd = (float4*)xl;
        for (int t = threadIdx.x; t < (RPB * C_IN) / 4; t += 256) xd[t] = xs[t];
    }
    __syncthreads();
    int wave = threadIdx.x >> 6, lane = threadIdx.x & 63;
#pragma unroll
    for (int nn = 0; nn < 4; nn++) {
        int row = wave * 4 + nn;
        float o0 = 0.f, o1 = 0.f;
#pragma unroll
        for (int k4 = 0; k4 < C_IN / 4; k4++) {
            float4 xk = *(const float4*)&xl[row * C_IN + k4 * 4];
            o0 += xk.x * Wlds[(k4 * 4 + 0) * C_H + lane];
            o1 += xk.y * Wlds[(k4 * 4 + 1) * C_H + lane];
            o0 += xk.z * Wlds[(k4 * 4 + 2) * C_H + lane];
            o1 += xk.w * Wlds[(k4 * 4 + 3) * C_H + lane];
        }
        out[((size_t)blockIdx.x * RPB + row) * C_H + lane] = f2bf(o0 + o1);
    }
}

// ---------------- fused layer: aggregate(hw_bf16) -> relu(+b) -> @Wnext -> bf16 ----------------
// 16 nodes/block, 4/wave. Gather: 8 edge-groups x 8 lanes (each lane = 8 bf16
// channels, one uint4/edge). Two nodes processed concurrently + 2-deep unroll
// = 4 independent row loads in flight; iterations = ceil(max(degA,degB)/16).

__global__ __launch_bounds__(256) void layer_kernel(const u32* __restrict__ hw,
                                                    const int* __restrict__ rowStart,
                                                    const int* __restrict__ cnt,
                                                    const int2* __restrict__ csr_sw,
                                                    const float* __restrict__ dinv,
                                                    const float* __restrict__ bias,
                                                    const float* __restrict__ Wnext,
                                                    u16* __restrict__ out) {
    __shared__ float Wlds[C_H * C_H];   // 16 KB
    __shared__ float hbuf[NPB][C_H];    // 4 KB
    for (int t = threadIdx.x; t < (C_H * C_H) / 4; t += 256)
        *(float4*)&Wlds[t * 4] = *(const float4*)&Wnext[t * 4];

    int wave = threadIdx.x >> 6, lane = threadIdx.x & 63;
    int g = lane >> 3;          // edge sub-group 0..7
    int r = lane & 7;           // channel chunk: channels 8r..8r+7
    int ibase = blockIdx.x * NPB + wave * 4;

    float b8[8];
    *(float4*)&b8[0] = *(const float4*)(bias + r * 8);
    *(float4*)&b8[4] = *(const float4*)(bias + r * 8 + 4);

#pragma unroll
    for (int pp = 0; pp < 2; pp++) {
        int iA = ibase + pp * 2, iB = iA + 1;
        int sA = rowStart[iA], dA = cnt[iA];
        int sB = rowStart[iB], dB = cnt[iB];
        float accA[8] = {0.f,0.f,0.f,0.f,0.f,0.f,0.f,0.f};
        float accB[8] = {0.f,0.f,0.f,0.f,0.f,0.f,0.f,0.f};
        int dmax = dA > dB ? dA : dB;

        for (int base = 0; base < dmax; base += 16) {
            int e0 = base + g, e1 = e0 + 8;
            bool vA0 = e0 < dA, vA1 = e1 < dA, vB0 = e0 < dB, vB1 = e1 < dB;
            int2 cA0 = csr_sw[sA + (vA0 ? e0 : 0)];
            int2 cA1 = csr_sw[sA + (vA1 ? e1 : 0)];
            int2 cB0 = csr_sw[sB + (vB0 ? e0 : 0)];
            int2 cB1 = csr_sw[sB + (vB1 ? e1 : 0)];
            uint4 rA0 = *(const uint4*)(hw + (size_t)cA0.x * C_HU + r * 4);
            uint4 rA1 = *(const uint4*)(hw + (size_t)cA1.x * C_HU + r * 4);
            uint4 rB0 = *(const uint4*)(hw + (size_t)cB0.x * C_HU + r * 4);
            uint4 rB1 = *(const uint4*)(hw + (size_t)cB1.x * C_HU + r * 4);
            float wA0 = vA0 ? __int_as_float(cA0.y) : 0.f;
            float wA1 = vA1 ? __int_as_float(cA1.y) : 0.f;
            float wB0 = vB0 ? __int_as_float(cB0.y) : 0.f;
            float wB1 = vB1 ? __int_as_float(cB1.y) : 0.f;
            fma8(accA, rA0, wA0); fma8(accA, rA1, wA1);
            fma8(accB, rB0, wB0); fma8(accB, rB1, wB1);
        }

        // reduce across the 8 edge-groups (lane bits 3,4,5)
#pragma unroll
        for (int c = 0; c < 8; c++) {
            accA[c] += __shfl_xor(accA[c], 8);
            accA[c] += __shfl_xor(accA[c], 16);
            accA[c] += __shfl_xor(accA[c], 32);
            accB[c] += __shfl_xor(accB[c], 8);
            accB[c] += __shfl_xor(accB[c], 16);
            accB[c] += __shfl_xor(accB[c], 32);
        }

        // finish both nodes: self-loop + bias + relu -> hbuf
#pragma unroll
        for (int q = 0; q < 2; q++) {
            int i = q ? iB : iA;
            float* acc = q ? accB : accA;
            float di = dinv[i];
            float sl = di * di;
            uint4 sv = *(const uint4*)(hw + (size_t)i * C_HU + r * 4);
            float h[8];
            h[0] = fmaxf(acc[0] + bflo(sv.x) * sl + b8[0], 0.f);
            h[1] = fmaxf(acc[1] + bfhi(sv.x) * sl + b8[1], 0.f);
            h[2] = fmaxf(acc[2] + bflo(sv.y) * sl + b8[2], 0.f);
            h[3] = fmaxf(acc[3] + bfhi(sv.y) * sl + b8[3], 0.f);
            h[4] = fmaxf(acc[4] + bflo(sv.z) * sl + b8[4], 0.f);
            h[5] = fmaxf(acc[5] + bfhi(sv.z) * sl + b8[5], 0.f);
            h[6] = fmaxf(acc[6] + bflo(sv.w) * sl + b8[6], 0.f);
            h[7] = fmaxf(acc[7] + bfhi(sv.w) * sl + b8[7], 0.f);
            if (g == 0) {
                *(float4*)&hbuf[wave * 4 + pp * 2 + q][r * 8]     = make_float4(h[0], h[1], h[2], h[3]);
                *(float4*)&hbuf[wave * 4 + pp * 2 + q][r * 8 + 4] = make_float4(h[4], h[5], h[6], h[7]);
            }
        }
    }
    __syncthreads();   // Wlds fill + hbuf visibility

    // GEMV: out[i][lane] = sum_k h[k] * Wnext[k][lane]
#pragma unroll
    for (int nn = 0; nn < 4; nn++) {
        float o0 = 0.f, o1 = 0.f;
#pragma unroll
        for (int k4 = 0; k4 < C_H / 4; k4++) {
            float4 hk = *(const float4*)&hbuf[wave * 4 + nn][k4 * 4];  // broadcast
            o0 += hk.x * Wlds[(k4 * 4 + 0) * C_H + lane];
            o1 += hk.y * Wlds[(k4 * 4 + 1) * C_H + lane];
            o0 += hk.z * Wlds[(k4 * 4 + 2) * C_H + lane];
            o1 += hk.w * Wlds[(k4 * 4 + 3) * C_H + lane];
        }
        out[(size_t)(ibase + nn) * C_H + lane] = f2bf(o0 + o1);
    }
}

// ---------------- pooling head ----------------

__global__ __launch_bounds__(256) void pool_kernel(const u16* __restrict__ hn,
                                                   float* __restrict__ poolbuf) {
    int g = blockIdx.x >> 4;
    int s = blockIdx.x & 15;
    int lane = threadIdx.x & 63;
    int rg = threadIdx.x >> 6;
    int stream = s * 4 + rg;
    float acc = 0.f;
    for (int r = stream; r < N_PER_G; r += 64)
        acc += bflo((u32)hn[(size_t)(g * N_PER_G + r) * C_H + lane]);
    __shared__ float red[4][C_H];
    red[rg][lane] = acc;
    __syncthreads();
    if (rg == 0) {
        float t = red[0][lane] + red[1][lane] + red[2][lane] + red[3][lane];
        atomicAdd(&poolbuf[g * C_H + lane], t);
    }
}

__global__ void poolwp_kernel(const float* __restrict__ poolbuf,
                              const float* __restrict__ Wp,
                              float* __restrict__ poolwp) {
    int g = blockIdx.x, c = threadIdx.x;
    float o = 0.f;
#pragma unroll 8
    for (int k = 0; k < C_H; k++) o += poolbuf[g * C_H + k] * Wp[k * C_H + c];
    poolwp[g * C_H + c] = o;
}

__global__ __launch_bounds__(256) void final_kernel(const u16* __restrict__ hn,
                                                    const float* __restrict__ poolwp,
                                                    const float* __restrict__ Wa,
                                                    float* __restrict__ out, int n) {
    int wave = threadIdx.x >> 6, lane = threadIdx.x & 63;
    int i = blockIdx.x * 4 + wave;
    if (i >= n) return;
    int g = i / N_PER_G;
    float v = fmaxf(bflo((u32)hn[(size_t)i * C_H + lane]), 0.f) * Wa[lane]
            + fmaxf(poolwp[g * C_H + lane], 0.f) * Wa[C_H + lane];
#pragma unroll
    for (int off = 32; off; off >>= 1) v += __shfl_down(v, off);
    if (lane == 0) out[i] = tanhf(v);
}

// ---------------- launch ----------------

extern "C" void kernel_launch(void* const* d_in, const int* in_sizes, int n_in,
                              void* d_out, int out_size, void* d_ws, size_t ws_size,
                              hipStream_t stream) {
    const float* x   = (const float*)d_in[0];
    const int*   ei  = (const int*)d_in[1];
    const float* W0  = (const float*)d_in[2];
    const float* b0  = (const float*)d_in[3];
    const float* Ws  = (const float*)d_in[4];
    const float* bs  = (const float*)d_in[5];
    const float* Wn  = (const float*)d_in[6];
    const float* Wp  = (const float*)d_in[7];
    const float* Wa  = (const float*)d_in[8];
    float* out = (float*)d_out;

    const int* e_src = ei;
    const int* e_dst = ei + N_EDGES;

    size_t off = 0;
    auto alloc = [&](size_t bytes) { size_t o = off; off = (off + bytes + 255) & ~(size_t)255; return o; };
    char* ws = (char*)d_ws;
    int*   cnt      = (int*)  (ws + alloc(N_NODES * 4));
    int*   rowStart = (int*)  (ws + alloc(N_NODES * 4));
    int*   cursor   = (int*)  (ws + alloc(N_NODES * 4));
    float* dinv     = (float*)(ws + alloc(N_NODES * 4));
    int*   bsum     = (int*)  (ws + alloc(NSB * 4));
    int2*  csr_sw   = (int2*) (ws + alloc((size_t)N_EDGES * 8));
    u16*   bufA     = (u16*)  (ws + alloc((size_t)N_NODES * C_H * 2));
    u16*   bufB     = (u16*)  (ws + alloc((size_t)N_NODES * C_H * 2));
    float* poolbuf  = (float*)(ws + alloc(N_GRAPH * C_H * 4));
    float* poolwp   = (float*)(ws + alloc(N_GRAPH * C_H * 4));

    hipMemsetAsync(cnt, 0, N_NODES * 4, stream);
    hipMemsetAsync(poolbuf, 0, N_GRAPH * C_H * 4, stream);

    const int EB = (N_EDGES + 255) / 256;
    count_kernel<<<EB, 256, 0, stream>>>(e_dst, cnt, N_EDGES);
    bsum_kernel<<<NSB, 256, 0, stream>>>(cnt, bsum);
    scan2_kernel<<<NSB, 256, 0, stream>>>(cnt, bsum, rowStart, cursor, dinv);
    scatter_kernel<<<EB, 256, 0, stream>>>(e_src, e_dst, cursor, dinv, csr_sw, N_EDGES);

    gemm0_kernel<<<N_NODES / RPB, 256, 0, stream>>>(x, W0, bufA);

    const int LB = N_NODES / NPB;   // 3125
    for (int k = 0; k < N_LAYER; k++) {
        const u16* hin  = (k & 1) ? bufB : bufA;
        u16*       hout = (k & 1) ? bufA : bufB;
        const float* bias  = (k == 0) ? b0 : (bs + (k - 1) * C_H);
        const float* Wnext = (k < N_LAYER - 1) ? (Ws + k * C_H * C_H) : Wn;
        layer_kernel<<<LB, 256, 0, stream>>>((const u32*)hin, rowStart, cnt, csr_sw,
                                             dinv, bias, Wnext, hout);
    }
    const u16* hn = bufB;   // layer 8 output

    pool_kernel<<<N_GRAPH * 16, 256, 0, stream>>>(hn, poolbuf);
    poolwp_kernel<<<N_GRAPH, C_H, 0, stream>>>(poolbuf, Wp, poolwp);
    final_kernel<<<N_NODES / 4, 256, 0, stream>>>(hn, poolwp, Wa, out, N_NODES);
}